// Round 1
// baseline (149.379 us; speedup 1.0000x reference)
//
#include <hip/hip_runtime.h>
#include <math.h>

// Problem constants (from reference): B=4, H=W=1024, GH=GW=16, GD=8, C=12
// grid layout in ws: gridbuf[((b*16+gh)*16+gw)*96 + z*12 + c]
// params layout in ws (after gridbuf): [w0 x16][w1 x16][w2 x16][bias x16][g2w x16][g2b]

#define GRIDBUF_FLOATS (4 * 16 * 16 * 96)

__device__ inline float fast_tanh(float x) {
    float ax = fabsf(x);
    float e  = __expf(2.0f * ax);
    float t  = 1.0f - 2.0f / (e + 1.0f);   // robust: e->inf gives t->1
    return copysignf(t, x);
}

// ---------------- Kernel 1: grid coefficients + folded guide params ----------
// blocks = B*256 (one per (b, gh*16+gw)), 128 threads
__global__ __launch_bounds__(128) void coeff_kernel(
    const float* __restrict__ lf,    // (B,64,16,16)
    const float* __restrict__ gf,    // (B,64)
    const float* __restrict__ fw,    // (96,64)
    const float* __restrict__ fb,    // (96,)
    const float* __restrict__ g1w,   // (16,3)
    const float* __restrict__ g1b,   // (16,)
    const float* __restrict__ bng,
    const float* __restrict__ bnb,
    const float* __restrict__ bnm,
    const float* __restrict__ bnv,
    const float* __restrict__ g2w,   // (1,16)
    const float* __restrict__ g2b,   // (1,)
    float* __restrict__ gridbuf,     // (B,16,16,96)
    float* __restrict__ params)      // 81 floats
{
    __shared__ float fused[64];
    const int blk = blockIdx.x;       // b*256 + pos
    const int b   = blk >> 8;
    const int pos = blk & 255;
    const int t   = threadIdx.x;

    if (t < 64) {
        float v = lf[(b * 64 + t) * 256 + pos] + gf[b * 64 + t];
        fused[t] = v > 0.0f ? v : 0.0f;
    }
    __syncthreads();

    if (t < 96) {
        float acc = fb[t];
        const float* wrow = fw + t * 64;
#pragma unroll
        for (int i = 0; i < 64; ++i) acc = fmaf(wrow[i], fused[i], acc);
        gridbuf[blk * 96 + t] = acc;
    }

    if (blk == 0 && t >= 96 && t < 112) {
        int k = t - 96;
        float a = bng[k] * rsqrtf(bnv[k] + 1e-5f);
        params[k]      = g1w[k * 3 + 0] * a;
        params[16 + k] = g1w[k * 3 + 1] * a;
        params[32 + k] = g1w[k * 3 + 2] * a;
        params[48 + k] = (g1b[k] - bnm[k]) * a + bnb[k];
        params[64 + k] = g2w[k];
        if (k == 0) params[80] = g2b[0];
    }
}

// ---------------- Kernel 2: guide + bilateral slice + apply + tanh -----------
// blocks = B*H (one per image row), 256 threads, 4 pixels/thread
__global__ __launch_bounds__(256) void slice_apply_kernel(
    const float* __restrict__ fullres,  // (B,3,1024,1024)
    const float* __restrict__ gridbuf,  // (B,16,16,96)
    const float* __restrict__ params,   // 81 floats
    float* __restrict__ out)            // (B,3,1024,1024)
{
    __shared__ __align__(16) float hrow[1536];  // [wc*96 + z*12 + c], h-lerped
    __shared__ float P[81];

    const int t = threadIdx.x;
    const int b = blockIdx.x >> 10;
    const int y = blockIdx.x & 1023;

    if (t < 81) P[t] = params[t];

    // h interpolation (constant for the whole row)
    float hg = (y + 0.5f) * 0.015625f - 0.5f;   // *(16/1024)
    int   h0 = (int)floorf(hg);
    float fh = hg - (float)h0;
    int hc0 = h0 < 0 ? 0 : h0;
    int hc1 = (h0 + 1) > 15 ? 15 : (h0 + 1);

    const float* row0 = gridbuf + (b * 256 + hc0 * 16) * 96;
    const float* row1 = gridbuf + (b * 256 + hc1 * 16) * 96;
    const float wfh0 = 1.0f - fh;
#pragma unroll
    for (int i = t; i < 1536; i += 256)
        hrow[i] = fmaf(wfh0, row0[i], fh * row1[i]);
    __syncthreads();

    const int xb = t << 2;                      // 4 pixels per thread
    const int pixbase = (y << 10) + xb;
    const int planeB = (b * 3) << 20;

    const float4 r4 = *(const float4*)(fullres + planeB + (0 << 20) + pixbase);
    const float4 g4 = *(const float4*)(fullres + planeB + (1 << 20) + pixbase);
    const float4 b4 = *(const float4*)(fullres + planeB + (2 << 20) + pixbase);

    float oR[4], oG[4], oB[4];

#pragma unroll
    for (int j = 0; j < 4; ++j) {
        const float r  = (j == 0) ? r4.x : (j == 1) ? r4.y : (j == 2) ? r4.z : r4.w;
        const float g  = (j == 0) ? g4.x : (j == 1) ? g4.y : (j == 2) ? g4.z : g4.w;
        const float bl = (j == 0) ? b4.x : (j == 1) ? b4.y : (j == 2) ? b4.z : b4.w;

        // ---- guide ----
        float acc = P[80];
#pragma unroll
        for (int k = 0; k < 16; ++k) {
            float gk = fmaf(r, P[k], fmaf(g, P[16 + k], fmaf(bl, P[32 + k], P[48 + k])));
            gk = gk > 0.0f ? gk : 0.0f;
            acc = fmaf(gk, P[64 + k], acc);
        }
        const float guide = 1.0f / (1.0f + __expf(-acc));

        // ---- trilinear slice (h already folded into hrow) ----
        float wg = (float)(xb + j) * 0.015625f + (0.5f * 0.015625f - 0.5f);
        int   w0 = (int)floorf(wg);
        float fw_ = wg - (float)w0;
        int wc0 = w0 < 0 ? 0 : w0;
        int wc1 = (w0 + 1) > 15 ? 15 : (w0 + 1);

        float zg = fmaf(guide, 8.0f, -0.5f);
        int   z0 = (int)floorf(zg);
        float fz = zg - (float)z0;
        int zc0 = z0 < 0 ? 0 : z0;
        int zc1 = (z0 + 1) > 7 ? 7 : (z0 + 1);

        float s[12];
#pragma unroll
        for (int c = 0; c < 12; ++c) s[c] = 0.0f;

#pragma unroll
        for (int dw = 0; dw < 2; ++dw) {
            const int   wc  = dw ? wc1 : wc0;
            const float whw = dw ? fw_ : (1.0f - fw_);
            const float w0z = whw * (1.0f - fz);
            const float w1z = whw * fz;
            const float* cell = hrow + wc * 96;
            const float4* p0 = (const float4*)(cell + zc0 * 12);
            const float4* p1 = (const float4*)(cell + zc1 * 12);
#pragma unroll
            for (int q = 0; q < 3; ++q) {
                float4 a  = p0[q];
                float4 bq = p1[q];
                s[q * 4 + 0] = fmaf(w0z, a.x, fmaf(w1z, bq.x, s[q * 4 + 0]));
                s[q * 4 + 1] = fmaf(w0z, a.y, fmaf(w1z, bq.y, s[q * 4 + 1]));
                s[q * 4 + 2] = fmaf(w0z, a.z, fmaf(w1z, bq.z, s[q * 4 + 2]));
                s[q * 4 + 3] = fmaf(w0z, a.w, fmaf(w1z, bq.w, s[q * 4 + 3]));
            }
        }

        // ---- apply affine color transform + tanh ----
        float Rv = fmaf(r, s[0], fmaf(g, s[1], fmaf(bl, s[2], s[9])));
        float Gv = fmaf(r, s[3], fmaf(g, s[4], fmaf(bl, s[5], s[10])));
        float Bv = fmaf(r, s[6], fmaf(g, s[7], fmaf(bl, s[8], s[11])));
        oR[j] = fast_tanh(Rv);
        oG[j] = fast_tanh(Gv);
        oB[j] = fast_tanh(Bv);
    }

    *(float4*)(out + planeB + (0 << 20) + pixbase) = make_float4(oR[0], oR[1], oR[2], oR[3]);
    *(float4*)(out + planeB + (1 << 20) + pixbase) = make_float4(oG[0], oG[1], oG[2], oG[3]);
    *(float4*)(out + planeB + (2 << 20) + pixbase) = make_float4(oB[0], oB[1], oB[2], oB[3]);
}

extern "C" void kernel_launch(void* const* d_in, const int* in_sizes, int n_in,
                              void* d_out, int out_size, void* d_ws, size_t ws_size,
                              hipStream_t stream) {
    const float* fullres = (const float*)d_in[0];
    const float* lf      = (const float*)d_in[1];
    const float* gf      = (const float*)d_in[2];
    const float* fw      = (const float*)d_in[3];
    const float* fb      = (const float*)d_in[4];
    const float* g1w     = (const float*)d_in[5];
    const float* g1b     = (const float*)d_in[6];
    const float* bng     = (const float*)d_in[7];
    const float* bnb     = (const float*)d_in[8];
    const float* bnm     = (const float*)d_in[9];
    const float* bnv     = (const float*)d_in[10];
    const float* g2w     = (const float*)d_in[11];
    const float* g2b     = (const float*)d_in[12];
    float* out = (float*)d_out;

    float* gridbuf = (float*)d_ws;
    float* params  = gridbuf + GRIDBUF_FLOATS;

    coeff_kernel<<<4 * 256, 128, 0, stream>>>(lf, gf, fw, fb, g1w, g1b,
                                              bng, bnb, bnm, bnv, g2w, g2b,
                                              gridbuf, params);
    slice_apply_kernel<<<4 * 1024, 256, 0, stream>>>(fullres, gridbuf, params, out);
}

// Round 3
// 139.380 us; speedup vs baseline: 1.0717x; 1.0717x over previous
//
#include <hip/hip_runtime.h>
#include <math.h>

// Problem constants: B=4, H=W=1024, GH=GW=16, GD=8, C=12
// ws layout: gridbuf[((b*16+gh)*16+gw)*96 + z*12 + c], then params[81]
// params: [w_r x16][w_g x16][w_b x16][bias x16][g2w x16][g2b]

#define GRIDBUF_FLOATS (4 * 16 * 16 * 96)
#define CELL_STRIDE 100   // padded from 96: (100 mod 32)=4 -> banks shift per wc

typedef float vfloat4 __attribute__((ext_vector_type(4)));  // native vec for nontemporal store

__device__ inline float fast_tanh(float x) {
    float ax = fabsf(x);
    float e  = __expf(2.0f * ax);
    float t  = 1.0f - 2.0f / (e + 1.0f);   // robust: e->inf gives t->1
    return copysignf(t, x);
}

// ---------------- Kernel 1: grid coefficients + folded guide params ----------
__global__ __launch_bounds__(128) void coeff_kernel(
    const float* __restrict__ lf,    // (B,64,16,16)
    const float* __restrict__ gf,    // (B,64)
    const float* __restrict__ fw,    // (96,64)
    const float* __restrict__ fb,    // (96,)
    const float* __restrict__ g1w,   // (16,3)
    const float* __restrict__ g1b,   // (16,)
    const float* __restrict__ bng,
    const float* __restrict__ bnb,
    const float* __restrict__ bnm,
    const float* __restrict__ bnv,
    const float* __restrict__ g2w,   // (1,16)
    const float* __restrict__ g2b,   // (1,)
    float* __restrict__ gridbuf,     // (B,16,16,96)
    float* __restrict__ params)      // 81 floats
{
    __shared__ float fused[64];
    const int blk = blockIdx.x;       // b*256 + pos
    const int b   = blk >> 8;
    const int pos = blk & 255;
    const int t   = threadIdx.x;

    if (t < 64) {
        float v = lf[(b * 64 + t) * 256 + pos] + gf[b * 64 + t];
        fused[t] = v > 0.0f ? v : 0.0f;
    }
    __syncthreads();

    if (t < 96) {
        float acc = fb[t];
        const float* wrow = fw + t * 64;
#pragma unroll
        for (int i = 0; i < 64; ++i) acc = fmaf(wrow[i], fused[i], acc);
        gridbuf[blk * 96 + t] = acc;
    }

    if (blk == 0 && t >= 96 && t < 112) {
        int k = t - 96;
        float a = bng[k] * rsqrtf(bnv[k] + 1e-5f);
        params[k]      = g1w[k * 3 + 0] * a;
        params[16 + k] = g1w[k * 3 + 1] * a;
        params[32 + k] = g1w[k * 3 + 2] * a;
        params[48 + k] = (g1b[k] - bnm[k]) * a + bnb[k];
        params[64 + k] = g2w[k];
        if (k == 0) params[80] = g2b[0];
    }
}

// ---------------- Kernel 2: guide + bilateral slice + apply + tanh -----------
// blocks = B*H (one per image row), 256 threads, 4 pixels/thread
__global__ __launch_bounds__(256) void slice_apply_kernel(
    const float* __restrict__ fullres,  // (B,3,1024,1024)
    const float* __restrict__ gridbuf,  // (B,16,16,96)
    const float* __restrict__ params,   // 81 floats (uniform -> s_load)
    float* __restrict__ out)            // (B,3,1024,1024)
{
    __shared__ __align__(16) float hrow[16 * CELL_STRIDE];  // padded h-lerped row

    const int t = threadIdx.x;
    const int b = blockIdx.x >> 10;
    const int y = blockIdx.x & 1023;

    // h interpolation (constant for the whole row)
    float hg = (y + 0.5f) * 0.015625f - 0.5f;
    int   h0 = (int)floorf(hg);
    float fh = hg - (float)h0;
    int hc0 = h0 < 0 ? 0 : h0;
    int hc1 = (h0 + 1) > 15 ? 15 : (h0 + 1);

    const float* row0 = gridbuf + (b * 256 + hc0 * 16) * 96;
    const float* row1 = gridbuf + (b * 256 + hc1 * 16) * 96;
    const float wfh0 = 1.0f - fh;
    // vectorized fill: 384 float4 lerps; a float4 never crosses a 96-float cell
#pragma unroll
    for (int i4 = t; i4 < 384; i4 += 256) {
        const int i   = i4 << 2;
        const int wc  = i / 96;
        const int rem = i - wc * 96;
        float4 a = *(const float4*)(row0 + i);
        float4 c = *(const float4*)(row1 + i);
        float4 r;
        r.x = fmaf(wfh0, a.x, fh * c.x);
        r.y = fmaf(wfh0, a.y, fh * c.y);
        r.z = fmaf(wfh0, a.z, fh * c.z);
        r.w = fmaf(wfh0, a.w, fh * c.w);
        *(float4*)(hrow + wc * CELL_STRIDE + rem) = r;
    }
    __syncthreads();

    const int xb = t << 2;                      // 4 pixels per thread
    const int pixbase = (y << 10) + xb;
    const int planeB = (b * 3) << 20;

    const float4 r4 = *(const float4*)(fullres + planeB + (0 << 20) + pixbase);
    const float4 g4 = *(const float4*)(fullres + planeB + (1 << 20) + pixbase);
    const float4 b4 = *(const float4*)(fullres + planeB + (2 << 20) + pixbase);

    float oR[4], oG[4], oB[4];

#pragma unroll
    for (int j = 0; j < 4; ++j) {
        const float r  = (j == 0) ? r4.x : (j == 1) ? r4.y : (j == 2) ? r4.z : r4.w;
        const float g  = (j == 0) ? g4.x : (j == 1) ? g4.y : (j == 2) ? g4.z : g4.w;
        const float bl = (j == 0) ? b4.x : (j == 1) ? b4.y : (j == 2) ? b4.z : b4.w;

        // ---- guide (params via uniform s_load; no LDS) ----
        float acc = params[80];
#pragma unroll
        for (int k = 0; k < 16; ++k) {
            float gk = fmaf(r, params[k],
                       fmaf(g, params[16 + k],
                       fmaf(bl, params[32 + k], params[48 + k])));
            gk = gk > 0.0f ? gk : 0.0f;
            acc = fmaf(gk, params[64 + k], acc);
        }
        const float guide = 1.0f / (1.0f + __expf(-acc));

        // ---- w coords via integer math: wg = (x+0.5)/64 - 0.5 ----
        const int x = xb + j;
        const int w0i = (x < 32) ? -1 : ((x - 32) >> 6);
        const float fw_ = ((float)x * 0.015625f + (0.0078125f - 0.5f)) - (float)w0i;
        const int wc0 = w0i < 0 ? 0 : w0i;
        const int wc1 = (w0i + 1) > 15 ? 15 : (w0i + 1);

        float zg = fmaf(guide, 8.0f, -0.5f);
        int   z0 = (int)floorf(zg);
        float fz = zg - (float)z0;
        int zc0 = z0 < 0 ? 0 : z0;
        int zc1 = (z0 + 1) > 7 ? 7 : (z0 + 1);

        float s[12];
#pragma unroll
        for (int c = 0; c < 12; ++c) s[c] = 0.0f;

#pragma unroll
        for (int dw = 0; dw < 2; ++dw) {
            const int   wc  = dw ? wc1 : wc0;
            const float whw = dw ? fw_ : (1.0f - fw_);
            const float w0z = whw * (1.0f - fz);
            const float w1z = whw * fz;
            const float* cell = hrow + wc * CELL_STRIDE;
            const float4* p0 = (const float4*)(cell + zc0 * 12);
            const float4* p1 = (const float4*)(cell + zc1 * 12);
#pragma unroll
            for (int q = 0; q < 3; ++q) {
                float4 a  = p0[q];
                float4 bq = p1[q];
                s[q * 4 + 0] = fmaf(w0z, a.x, fmaf(w1z, bq.x, s[q * 4 + 0]));
                s[q * 4 + 1] = fmaf(w0z, a.y, fmaf(w1z, bq.y, s[q * 4 + 1]));
                s[q * 4 + 2] = fmaf(w0z, a.z, fmaf(w1z, bq.z, s[q * 4 + 2]));
                s[q * 4 + 3] = fmaf(w0z, a.w, fmaf(w1z, bq.w, s[q * 4 + 3]));
            }
        }

        // ---- apply affine color transform + tanh ----
        float Rv = fmaf(r, s[0], fmaf(g, s[1], fmaf(bl, s[2], s[9])));
        float Gv = fmaf(r, s[3], fmaf(g, s[4], fmaf(bl, s[5], s[10])));
        float Bv = fmaf(r, s[6], fmaf(g, s[7], fmaf(bl, s[8], s[11])));
        oR[j] = fast_tanh(Rv);
        oG[j] = fast_tanh(Gv);
        oB[j] = fast_tanh(Bv);
    }

    vfloat4 vR = { oR[0], oR[1], oR[2], oR[3] };
    vfloat4 vG = { oG[0], oG[1], oG[2], oG[3] };
    vfloat4 vB = { oB[0], oB[1], oB[2], oB[3] };
    __builtin_nontemporal_store(vR, (vfloat4*)(out + planeB + (0 << 20) + pixbase));
    __builtin_nontemporal_store(vG, (vfloat4*)(out + planeB + (1 << 20) + pixbase));
    __builtin_nontemporal_store(vB, (vfloat4*)(out + planeB + (2 << 20) + pixbase));
}

extern "C" void kernel_launch(void* const* d_in, const int* in_sizes, int n_in,
                              void* d_out, int out_size, void* d_ws, size_t ws_size,
                              hipStream_t stream) {
    const float* fullres = (const float*)d_in[0];
    const float* lf      = (const float*)d_in[1];
    const float* gf      = (const float*)d_in[2];
    const float* fw      = (const float*)d_in[3];
    const float* fb      = (const float*)d_in[4];
    const float* g1w     = (const float*)d_in[5];
    const float* g1b     = (const float*)d_in[6];
    const float* bng     = (const float*)d_in[7];
    const float* bnb     = (const float*)d_in[8];
    const float* bnm     = (const float*)d_in[9];
    const float* bnv     = (const float*)d_in[10];
    const float* g2w     = (const float*)d_in[11];
    const float* g2b     = (const float*)d_in[12];
    float* out = (float*)d_out;

    float* gridbuf = (float*)d_ws;
    float* params  = gridbuf + GRIDBUF_FLOATS;

    coeff_kernel<<<4 * 256, 128, 0, stream>>>(lf, gf, fw, fb, g1w, g1b,
                                              bng, bnb, bnm, bnv, g2w, g2b,
                                              gridbuf, params);
    slice_apply_kernel<<<4 * 1024, 256, 0, stream>>>(fullres, gridbuf, params, out);
}

// Round 4
// 133.561 us; speedup vs baseline: 1.1184x; 1.0436x over previous
//
#include <hip/hip_runtime.h>
#include <math.h>

// Problem constants: B=4, H=W=1024, GH=GW=16, GD=8, C=12
// ws layout: gridbuf[((b*16+gh)*16+gw)*96 + z*12 + c], then params[81]
// params: [w_r x16][w_g x16][w_b x16][bias x16][g2w x16][g2b]

#define GRIDBUF_FLOATS (4 * 16 * 16 * 96)
#define CELL_STRIDE 100   // padded from 96: (100 mod 32)=4 -> banks shift per wc

typedef float  vfloat4 __attribute__((ext_vector_type(4)));
typedef float  f2      __attribute__((ext_vector_type(2)));
typedef int    i2      __attribute__((ext_vector_type(2)));

__device__ inline f2 splat2(float x) { f2 v; v.x = x; v.y = x; return v; }

// packed tanh on a pixel pair: t = sign(x) * (1 - 2/(exp(2|x|)+1))
__device__ inline f2 fast_tanh2(f2 x) {
    f2 ax = __builtin_elementwise_abs(x);
    f2 xx = ax + ax;
    f2 e;
    e.x = __expf(xx.x);
    e.y = __expf(xx.y);
    f2 ep1 = e + splat2(1.0f);
    f2 r;
    r.x = __builtin_amdgcn_rcpf(ep1.x);
    r.y = __builtin_amdgcn_rcpf(ep1.y);
    f2 t = splat2(1.0f) - (r + r);          // in [0,1], e=inf -> t=1
    i2 sgn = __builtin_bit_cast(i2, x) & (i2){(int)0x80000000, (int)0x80000000};
    return __builtin_bit_cast(f2, __builtin_bit_cast(i2, t) | sgn);
}

// ---------------- Kernel 1: grid coefficients + folded guide params ----------
__global__ __launch_bounds__(128) void coeff_kernel(
    const float* __restrict__ lf,    // (B,64,16,16)
    const float* __restrict__ gf,    // (B,64)
    const float* __restrict__ fw,    // (96,64)
    const float* __restrict__ fb,    // (96,)
    const float* __restrict__ g1w,   // (16,3)
    const float* __restrict__ g1b,   // (16,)
    const float* __restrict__ bng,
    const float* __restrict__ bnb,
    const float* __restrict__ bnm,
    const float* __restrict__ bnv,
    const float* __restrict__ g2w,   // (1,16)
    const float* __restrict__ g2b,   // (1,)
    float* __restrict__ gridbuf,     // (B,16,16,96)
    float* __restrict__ params)      // 81 floats
{
    __shared__ float fused[64];
    const int blk = blockIdx.x;       // b*256 + pos
    const int b   = blk >> 8;
    const int pos = blk & 255;
    const int t   = threadIdx.x;

    if (t < 64) {
        float v = lf[(b * 64 + t) * 256 + pos] + gf[b * 64 + t];
        fused[t] = v > 0.0f ? v : 0.0f;
    }
    __syncthreads();

    if (t < 96) {
        float acc = fb[t];
        const float* wrow = fw + t * 64;
#pragma unroll
        for (int i = 0; i < 64; ++i) acc = fmaf(wrow[i], fused[i], acc);
        gridbuf[blk * 96 + t] = acc;
    }

    if (blk == 0 && t >= 96 && t < 112) {
        int k = t - 96;
        float a = bng[k] * rsqrtf(bnv[k] + 1e-5f);
        params[k]      = g1w[k * 3 + 0] * a;
        params[16 + k] = g1w[k * 3 + 1] * a;
        params[32 + k] = g1w[k * 3 + 2] * a;
        params[48 + k] = (g1b[k] - bnm[k]) * a + bnb[k];
        params[64 + k] = g2w[k];
        if (k == 0) params[80] = g2b[0];
    }
}

// ---------------- Kernel 2: guide + bilateral slice + apply + tanh -----------
// blocks = B*H (one per image row), 256 threads, 4 pixels/thread.
// Core math is float2-packed -> v_pk_fma_f32 (gfx950 packed fp32 dual-rate).
__global__ __launch_bounds__(256) void slice_apply_kernel(
    const float* __restrict__ fullres,  // (B,3,1024,1024)
    const float* __restrict__ gridbuf,  // (B,16,16,96)
    const float* __restrict__ params,   // 81 floats (uniform -> s_load)
    float* __restrict__ out)            // (B,3,1024,1024)
{
    __shared__ __align__(16) float hrow[16 * CELL_STRIDE];  // padded h-lerped row

    const int t = threadIdx.x;
    const int b = blockIdx.x >> 10;
    const int y = blockIdx.x & 1023;

    // h interpolation (constant for the whole row)
    float hg = (y + 0.5f) * 0.015625f - 0.5f;
    int   h0 = (int)floorf(hg);
    float fh = hg - (float)h0;
    int hc0 = h0 < 0 ? 0 : h0;
    int hc1 = (h0 + 1) > 15 ? 15 : (h0 + 1);

    const float* row0 = gridbuf + (b * 256 + hc0 * 16) * 96;
    const float* row1 = gridbuf + (b * 256 + hc1 * 16) * 96;
    const float wfh0 = 1.0f - fh;
#pragma unroll
    for (int i4 = t; i4 < 384; i4 += 256) {
        const int i   = i4 << 2;
        const int wc  = i / 96;
        const int rem = i - wc * 96;
        float4 a = *(const float4*)(row0 + i);
        float4 c = *(const float4*)(row1 + i);
        float4 r;
        r.x = fmaf(wfh0, a.x, fh * c.x);
        r.y = fmaf(wfh0, a.y, fh * c.y);
        r.z = fmaf(wfh0, a.z, fh * c.z);
        r.w = fmaf(wfh0, a.w, fh * c.w);
        *(float4*)(hrow + wc * CELL_STRIDE + rem) = r;
    }
    __syncthreads();

    const int xb = t << 2;                      // 4 pixels per thread
    const int pixbase = (y << 10) + xb;
    const int planeB = (b * 3) << 20;

    const float4 r4 = *(const float4*)(fullres + planeB + (0 << 20) + pixbase);
    const float4 g4 = *(const float4*)(fullres + planeB + (1 << 20) + pixbase);
    const float4 b4 = *(const float4*)(fullres + planeB + (2 << 20) + pixbase);

    // w cell indices: uniform across this thread's 4 pixels
    // (boundaries at x = 32 + 64k are multiples of 4, so a 4-group never straddles)
    const int w0i = (xb < 32) ? -1 : ((xb - 32) >> 6);
    const int wc0 = w0i < 0 ? 0 : w0i;
    const int wc1 = (w0i + 1) > 15 ? 15 : (w0i + 1);
    const float* cell0 = hrow + wc0 * CELL_STRIDE;
    const float* cell1 = hrow + wc1 * CELL_STRIDE;

    float Rv[4], Gv[4], Bv[4];

#pragma unroll
    for (int pp = 0; pp < 2; ++pp) {
        f2 rr, gg, bb;
        if (pp == 0) { rr = (f2){r4.x, r4.y}; gg = (f2){g4.x, g4.y}; bb = (f2){b4.x, b4.y}; }
        else         { rr = (f2){r4.z, r4.w}; gg = (f2){g4.z, g4.w}; bb = (f2){b4.z, b4.w}; }

        // ---- guide MLP, packed across the pixel pair ----
        f2 acc = splat2(params[80]);
#pragma unroll
        for (int k = 0; k < 16; ++k) {
            f2 gk = __builtin_elementwise_fma(rr, splat2(params[k]),
                    __builtin_elementwise_fma(gg, splat2(params[16 + k]),
                    __builtin_elementwise_fma(bb, splat2(params[32 + k]),
                                              splat2(params[48 + k]))));
            gk = __builtin_elementwise_max(gk, splat2(0.0f));
            acc = __builtin_elementwise_fma(gk, splat2(params[64 + k]), acc);
        }
        // sigmoid -> z coordinate: zg = 8*sigma(acc) - 0.5
        f2 zg;
        zg.x = fmaf(8.0f, __builtin_amdgcn_rcpf(1.0f + __expf(-acc.x)), -0.5f);
        zg.y = fmaf(8.0f, __builtin_amdgcn_rcpf(1.0f + __expf(-acc.y)), -0.5f);

#pragma unroll
        for (int px = 0; px < 2; ++px) {
            const int j = pp * 2 + px;
            const float zgp = px ? zg.y : zg.x;
            int   z0 = (int)floorf(zgp);
            float fz = zgp - (float)z0;
            int zc0 = z0 < 0 ? 0 : z0;
            int zc1 = (z0 + 1) > 7 ? 7 : (z0 + 1);

            const int x = xb + j;
            const float fw_ = (float)x * 0.015625f + (0.0078125f - 0.5f) - (float)w0i;
            const float ww0 = 1.0f - fw_;
            const f2 W00 = splat2(ww0 * (1.0f - fz));
            const f2 W01 = splat2(ww0 * fz);
            const f2 W10 = splat2(fw_ * (1.0f - fz));
            const f2 W11 = splat2(fw_ * fz);

            const float4* p00 = (const float4*)(cell0 + zc0 * 12);
            const float4* p01 = (const float4*)(cell0 + zc1 * 12);
            const float4* p10 = (const float4*)(cell1 + zc0 * 12);
            const float4* p11 = (const float4*)(cell1 + zc1 * 12);

            f2 sa[6];   // channel-packed accumulators: {s0,s1}..{s10,s11}
#pragma unroll
            for (int q = 0; q < 3; ++q) {
                float4 a = p00[q], c = p01[q], d = p10[q], e = p11[q];
                f2 alo = (f2){a.x, a.y}, ahi = (f2){a.z, a.w};
                f2 clo = (f2){c.x, c.y}, chi = (f2){c.z, c.w};
                f2 dlo = (f2){d.x, d.y}, dhi = (f2){d.z, d.w};
                f2 elo = (f2){e.x, e.y}, ehi = (f2){e.z, e.w};
                sa[2 * q] =
                    __builtin_elementwise_fma(alo, W00,
                    __builtin_elementwise_fma(clo, W01,
                    __builtin_elementwise_fma(dlo, W10, elo * W11)));
                sa[2 * q + 1] =
                    __builtin_elementwise_fma(ahi, W00,
                    __builtin_elementwise_fma(chi, W01,
                    __builtin_elementwise_fma(dhi, W10, ehi * W11)));
            }

            // chunks: sa0={s0,s1} sa1={s2,s3} sa2={s4,s5} sa3={s6,s7} sa4={s8,s9} sa5={s10,s11}
            const float r  = px ? rr.y : rr.x;
            const float g  = px ? gg.y : gg.x;
            const float bl = px ? bb.y : bb.x;
            Rv[j] = fmaf(r, sa[0].x, fmaf(g, sa[0].y, fmaf(bl, sa[1].x, sa[4].y)));
            Gv[j] = fmaf(r, sa[1].y, fmaf(g, sa[2].x, fmaf(bl, sa[2].y, sa[5].x)));
            Bv[j] = fmaf(r, sa[3].x, fmaf(g, sa[3].y, fmaf(bl, sa[4].x, sa[5].y)));
        }
    }

    // packed tanh epilogue
    f2 tR0 = fast_tanh2((f2){Rv[0], Rv[1]});
    f2 tR1 = fast_tanh2((f2){Rv[2], Rv[3]});
    f2 tG0 = fast_tanh2((f2){Gv[0], Gv[1]});
    f2 tG1 = fast_tanh2((f2){Gv[2], Gv[3]});
    f2 tB0 = fast_tanh2((f2){Bv[0], Bv[1]});
    f2 tB1 = fast_tanh2((f2){Bv[2], Bv[3]});

    vfloat4 vR = {tR0.x, tR0.y, tR1.x, tR1.y};
    vfloat4 vG = {tG0.x, tG0.y, tG1.x, tG1.y};
    vfloat4 vB = {tB0.x, tB0.y, tB1.x, tB1.y};
    __builtin_nontemporal_store(vR, (vfloat4*)(out + planeB + (0 << 20) + pixbase));
    __builtin_nontemporal_store(vG, (vfloat4*)(out + planeB + (1 << 20) + pixbase));
    __builtin_nontemporal_store(vB, (vfloat4*)(out + planeB + (2 << 20) + pixbase));
}

extern "C" void kernel_launch(void* const* d_in, const int* in_sizes, int n_in,
                              void* d_out, int out_size, void* d_ws, size_t ws_size,
                              hipStream_t stream) {
    const float* fullres = (const float*)d_in[0];
    const float* lf      = (const float*)d_in[1];
    const float* gf      = (const float*)d_in[2];
    const float* fw      = (const float*)d_in[3];
    const float* fb      = (const float*)d_in[4];
    const float* g1w     = (const float*)d_in[5];
    const float* g1b     = (const float*)d_in[6];
    const float* bng     = (const float*)d_in[7];
    const float* bnb     = (const float*)d_in[8];
    const float* bnm     = (const float*)d_in[9];
    const float* bnv     = (const float*)d_in[10];
    const float* g2w     = (const float*)d_in[11];
    const float* g2b     = (const float*)d_in[12];
    float* out = (float*)d_out;

    float* gridbuf = (float*)d_ws;
    float* params  = gridbuf + GRIDBUF_FLOATS;

    coeff_kernel<<<4 * 256, 128, 0, stream>>>(lf, gf, fw, fb, g1w, g1b,
                                              bng, bnb, bnm, bnv, g2w, g2b,
                                              gridbuf, params);
    slice_apply_kernel<<<4 * 1024, 256, 0, stream>>>(fullres, gridbuf, params, out);
}